// Round 6
// baseline (264.500 us; speedup 1.0000x reference)
//
#include <hip/hip_runtime.h>
#include <hip/hip_fp16.h>
#include <math.h>

#define N_CELLS 16384
#define HID 512
#define IND 512

// ---- k_front roles ----
#define ROT_BLOCKS  2048    // 256 cell-tiles x 8 ch-tiles, each 64 cells x 64 ch
#define PUMP_BLOCKS 1024    // 16 cells per block (16 lanes per cell, 8-deep loads)

// ---- k_finall ----
#define CPB 16                          // cells per cell-block (LDS tile 16x512 u32 = 32 KB)
#define CELL_BLOCKS (N_CELLS / CPB)     // 1024
#define PRED_BLOCKS 128                 // 4 pred rows per block

// ---- workspace layout (bytes) ----
#define CNT_OFF   0                                   // int[2]: gates (memset to 0 by host)
#define LASB_OFF  1024                                // u32[512]: lasing bitmask (memset to 0)
#define EMIS_OFF  8192                                // float2[512]: per-channel emission sums
#define CAV_OFF   16384                               // float[1536]: cav_new re|im|old phase
#define VPART_OFF 32768                               // float2[CELL_BLOCKS]
#define ROT_OFF   (1<<20)                             // u32 Y^T[512][16384]: packed half2(re,im)
#define NST_OFF   (ROT_OFF + (size_t)N_CELLS*HID*4)   // u32 NST^T[512][16384]

typedef unsigned int u32;

__device__ inline __half2 u2h(u32 u) { union { u32 u; __half2 h; } x; x.u = u; return x.h; }
__device__ inline u32 h2u(__half2 h) { union { u32 u; __half2 h; } x; x.h = h; return x.u; }
__device__ inline u32 packh2(float re, float im) { return h2u(__floats2half2_rn(re, im)); }
__device__ inline float2 unph2(u32 u) { __half2 h = u2h(u); return make_float2(__low2float(h), __high2float(h)); }

#if __has_builtin(__builtin_amdgcn_fdot2)
typedef _Float16 hv2 __attribute__((ext_vector_type(2)));
__device__ inline float dot2u(u32 a, u32 b) {
    union { u32 u; hv2 h; } x, y; x.u = a; y.u = b;
    return __builtin_amdgcn_fdot2(x.h, y.h, 0.f, false);   // re*re' + im*im' in f32
}
#else
__device__ inline float dot2u(u32 a, u32 b) {
    float2 af = unph2(a), bf = unph2(b);
    return fmaf(af.x, bf.x, af.y * bf.y);
}
#endif

// acc += d * q  where d = y.q  (cos-coupling identity on y = s/sqrt(|s|))
__device__ inline void accnb(__half2& acc, u32 y, u32 q) {
    float d = dot2u(y, q);
    acc = __hfma2(__float2half2_rn(d), u2h(q), acc);
}

// new = 0.7*s + 0.002*|s|^{-1/2}*acc ; s = |s|^{1/2} * y ; emission sum if lasing
__device__ inline u32 fincell(u32 y, __half2 acc, int las, float& emR, float& emI) {
    float2 yf = unph2(y);
    float a  = fmaf(yf.x, yf.x, yf.y * yf.y);   // |y|^2 = |s|
    float rs = rsqrtf(a);
    float sq = a * rs;
    float2 af = make_float2(__low2float(acc), __high2float(acc));
    float nr = 0.7f * sq * yf.x + 0.002f * rs * af.x;
    float ni = 0.7f * sq * yf.y + 0.002f * rs * af.y;
    if (las) { emR += nr; emI += ni; }
    return packh2(nr, ni);
}

// rotate by exp(i*0.1*w), scale by |s|^{-1/2}, pack half2(re,im)
__device__ inline u32 rot1(float re, float im, float w) {
    float sc = rsqrtf(sqrtf(fmaf(re, re, im * im)));
    float s, c;
    __sincosf(0.1f * w, &s, &c);
    return packh2((re * c - im * s) * sc, (re * s + im * c) * sc);
}

__device__ inline float dot4(float4 a, float4 b) {
    return a.x * b.x + a.y * b.y + a.z * b.z + a.w * b.w;
}

// ---------------------------------------------------------------------------
// Kernel 1: rotation + |s|^{-1/2} scaling, written TRANSPOSED (Y^T[ch][cell])
// via a 64x64 LDS transpose tile (pitch 65). sched_barrier(0) pins the 12
// staged float4 loads ABOVE the compute (round-5 lesson: source-order
// hoisting alone gets re-serialized; VGPR stayed 32).
// Pump role: 16 cells/block, 16 lanes/cell, 8-deep pump_W row loads,
// lasing flags packed to a bitmask via ballot + atomicOr.
__global__ __launch_bounds__(256, 3) void k_front(const float* __restrict__ cr,
        const float* __restrict__ ci, const float* __restrict__ pv,
        u32* __restrict__ yt,
        const float* __restrict__ x, const float* __restrict__ pW,
        const float* __restrict__ pb, const float* __restrict__ excited,
        u32* __restrict__ lasb) {
    int b = blockIdx.x, tid = threadIdx.x;
    if (b < ROT_BLOCKS) {
        __shared__ u32 tile[64 * 65];
        int cb = b >> 3, hb = b & 7;
        const float4* cr4 = (const float4*)cr;
        const float4* ci4 = (const float4*)ci;
        const float4* pv4 = (const float4*)pv;
        float4 A[4], Bv[4], Wv[4];
        int row[4], c4[4];
#pragma unroll
        for (int j = 0; j < 4; ++j) {                   // 12 loads issued back-to-back
            int idx = tid + 256 * j;
            row[j] = idx >> 4; c4[j] = idx & 15;
            size_t g = (size_t)(cb * 64 + row[j]) * 128 + hb * 16 + c4[j];
            A[j] = cr4[g]; Bv[j] = ci4[g]; Wv[j] = pv4[g];
        }
        __builtin_amdgcn_sched_barrier(0);              // loads may not sink below
#pragma unroll
        for (int j = 0; j < 4; ++j) {
            u32* dst = &tile[row[j] * 65 + (c4[j] << 2)];
            dst[0] = rot1(A[j].x, Bv[j].x, Wv[j].x);
            dst[1] = rot1(A[j].y, Bv[j].y, Wv[j].y);
            dst[2] = rot1(A[j].z, Bv[j].z, Wv[j].z);
            dst[3] = rot1(A[j].w, Bv[j].w, Wv[j].w);
        }
        __syncthreads();
        uint4 v[4];
#pragma unroll
        for (int j = 0; j < 4; ++j) {                   // gather all, then store all
            int idx = tid + 256 * j;
            int chr = idx >> 4, q = idx & 15;
            v[j].x = tile[(q * 4 + 0) * 65 + chr];
            v[j].y = tile[(q * 4 + 1) * 65 + chr];
            v[j].z = tile[(q * 4 + 2) * 65 + chr];
            v[j].w = tile[(q * 4 + 3) * 65 + chr];
        }
#pragma unroll
        for (int j = 0; j < 4; ++j) {
            int idx = tid + 256 * j;
            int chr = idx >> 4, q = idx & 15;
            ((uint4*)(yt + (size_t)(hb * 64 + chr) * N_CELLS + cb * 64))[q] = v[j];
        }
    } else {
        // ---- pump: block = 16 cells; 16 lanes per cell read the 512-row ----
        int c0 = (b - ROT_BLOCKS) * 16;
        int cell = c0 + (tid >> 4);
        int l16 = tid & 15;
        int lane = tid & 63;
        const float4* w4 = (const float4*)(pW + (size_t)cell * IND);
        const float4* x4 = (const float4*)x;
        float4 wv[8];
#pragma unroll
        for (int k = 0; k < 8; ++k) wv[k] = w4[l16 + 16 * k];   // 8 in flight
        __builtin_amdgcn_sched_barrier(0);
        float acc = 0.f;
#pragma unroll
        for (int k = 0; k < 8; ++k) acc += dot4(wv[k], x4[l16 + 16 * k]);
#pragma unroll
        for (int o = 1; o < 16; o <<= 1) acc += __shfl_xor(acc, o, 64);
        int flag = 0;
        if (l16 == 0) {
            float p = 1.f / (1.f + expf(-(acc + pb[cell])));
            float e = excited[cell] * 0.95f + p * 0.05f;
            e = fminf(fmaxf(e, 0.f), 1.f);
            flag = (e > 0.5f) ? 1 : 0;
        }
        unsigned long long bal = __ballot(flag);        // bits 0,16,32,48 valid
        if (lane == 0) {
            u32 val = (u32)(bal & 1) | ((u32)(bal >> 16) & 1) << 1
                    | ((u32)(bal >> 32) & 1) << 2 | ((u32)(bal >> 48) & 1) << 3;
            atomicOr(&lasb[cell >> 5], val << (cell & 31));   // cell%4==0 here
        }
    }
}

// ---------------------------------------------------------------------------
// Kernel 2: neighbor coupling, one block per CHANNEL. 1024 threads (round-5
// lesson: 64KB LDS caps at 2 blocks/CU, so 256-thread blocks = 8 waves/CU =
// latency-bound; 1024 threads = 32 waves/CU at the same LDS). Lasing flags
// come from the 2KB bitmask (saves 33MB of lasv traffic). Counter-gated tail
// computes cavity_new + old phase once.
__global__ __launch_bounds__(1024, 8) void k_coup(const u32* __restrict__ yt,
                                                  const u32* __restrict__ lasb,
                                                  u32* __restrict__ nstT,
                                                  float2* __restrict__ emisT,
                                                  const float* __restrict__ cavr,
                                                  const float* __restrict__ cavi,
                                                  float* __restrict__ cavws,
                                                  int* __restrict__ cnt) {
    __shared__ __align__(16) u32 col[N_CELLS];          // exactly 64 KiB
    int ch = blockIdx.x, tid = threadIdx.x;
    const uint4* src = (const uint4*)(yt + (size_t)ch * N_CELLS);
    uint4* cdst = (uint4*)col;
    {
        uint4 st[4];
#pragma unroll
        for (int k = 0; k < 4; ++k) st[k] = src[tid + 1024 * k];   // 4 in flight
        __builtin_amdgcn_sched_barrier(0);
#pragma unroll
        for (int k = 0; k < 4; ++k) cdst[tid + 1024 * k] = st[k];
    }
    __syncthreads();

    float emR = 0.f, emI = 0.f;
    int nlo = 0;
    uint4* outp = (uint4*)(nstT + (size_t)ch * N_CELLS);
#pragma unroll 2
    for (int j = 0; j < 4; ++j) {
        int s = tid + 1024 * j;
        u32 f = (lasb[s >> 3] >> ((s & 7) * 4)) & 0xF;  // 4 cells' flags
        int c = s << 2;                                 // quad base cell
        uint4 sq = *(const uint4*)&col[c];
        __half2 z = __floats2half2_rn(0.f, 0.f);
        __half2 a0 = z, a1 = z, a2 = z, a3 = z;
#pragma unroll
        for (int bb = 2; bb < 14; ++bb) {               // 12 external flips
            uint4 q = *(const uint4*)&col[c ^ (1 << bb)];
            accnb(a0, sq.x, q.x);
            accnb(a1, sq.y, q.y);
            accnb(a2, sq.z, q.z);
            accnb(a3, sq.w, q.w);
        }
        u32 qm = col[(c - 1) & (N_CELLS - 1)];          // ring extra of cell c   (even -> c-1)
        u32 qp = col[(c + 4) & (N_CELLS - 1)];          // ring extra of cell c+3 (odd  -> c+4)
        accnb(a0, sq.x, sq.y); accnb(a0, sq.x, sq.z); accnb(a0, sq.x, qm);
        accnb(a1, sq.y, sq.x); accnb(a1, sq.y, sq.w); accnb(a1, sq.y, sq.z);
        accnb(a2, sq.z, sq.w); accnb(a2, sq.z, sq.x); accnb(a2, sq.z, sq.y);
        accnb(a3, sq.w, sq.z); accnb(a3, sq.w, sq.y); accnb(a3, sq.w, qp);
        nlo += __popc(f);
        uint4 ov;
        ov.x = fincell(sq.x, a0, f & 1, emR, emI);
        ov.y = fincell(sq.y, a1, f & 2, emR, emI);
        ov.z = fincell(sq.z, a2, f & 4, emR, emI);
        ov.w = fincell(sq.w, a3, f & 8, emR, emI);
        outp[s] = ov;
    }
    __syncthreads();                                    // col reads done -> reuse as scratch
#pragma unroll
    for (int o = 32; o; o >>= 1) {
        emR += __shfl_xor(emR, o, 64);
        emI += __shfl_xor(emI, o, 64);
        nlo += __shfl_xor(nlo, o, 64);
    }
    float* scr = (float*)col;
    int* iscr = (int*)col;
    int wid = tid >> 6, lane = tid & 63;
    if (lane == 0) { scr[wid] = emR; scr[16 + wid] = emI; iscr[32 + wid] = nlo; }
    __syncthreads();
    if (tid == 0) {
        float sr = 0.f, si = 0.f; int sn = 0;
#pragma unroll
        for (int k = 0; k < 16; ++k) { sr += scr[k]; si += scr[16 + k]; sn += iscr[32 + k]; }
        emisT[ch] = make_float2(sr, si);
        iscr[48] = sn;
        __threadfence();
        int old = atomicAdd(cnt, 1);
        iscr[49] = (old == HID - 1) ? 1 : 0;
    }
    __syncthreads();
    if (iscr[49]) {
        // ---- TAIL: compute cavity_new + old phase once ----
        __threadfence();
        int nl = iscr[48];
        float inv = (nl > 0) ? 0.2f / (float)nl : 0.f;
        if (tid < 512) {
            int i = tid;
            float crv = cavr[i], civ = cavi[i];
            float2 e = emisT[i];
            cavws[i]        = (nl > 0) ? 0.8f * crv + e.x * inv : crv;
            cavws[512 + i]  = (nl > 0) ? 0.8f * civ + e.y * inv : civ;
            cavws[1024 + i] = atan2f(civ, crv);
        }
    }
}

// ---------------------------------------------------------------------------
// Kernel 3: finalize + var + pred. Cell role: block = 16 cells; the
// [512ch x 16cell] slab is loaded with coalesced 64B row segments into a
// 32KB XOR-swizzled LDS tile, then 16 threads/cell stream 32 ch each.
// sched_barrier pins the 8 slab loads above the scatter.
__global__ __launch_bounds__(256, 2) void k_finall(const u32* __restrict__ nstT,
        const u32* __restrict__ lasb, const float* __restrict__ cavws,
        const float* __restrict__ dW, const float* __restrict__ db,
        float2* __restrict__ vpart, int* __restrict__ cnt2,
        float* __restrict__ out) {
    int b = blockIdx.x, t = threadIdx.x;
    int wid = t >> 6, lane = t & 63;
    if (b < CELL_BLOCKS) {
        __shared__ __align__(16) u32 tile[CPB * HID];   // 32 KB
        __shared__ __align__(16) float scav[1536];      // cav re|im|phase
        __shared__ float w1[4], w2[4];
        __shared__ int slast;
        __shared__ double l1s[4], l2s[4];

        int c0 = b * CPB;
        uint4 ld[8]; int chv[8], qv[8];
#pragma unroll
        for (int j = 0; j < 8; ++j) {                   // 8 loads in flight
            int idx = t + 256 * j;                      // 0..2047
            chv[j] = idx >> 2; qv[j] = idx & 3;
            ld[j] = ((const uint4*)(nstT + (size_t)chv[j] * N_CELLS + c0))[qv[j]];
        }
        const float4* c4p = (const float4*)cavws;
#pragma unroll
        for (int k2 = 0; k2 < 2; ++k2) {
            int i = t + 256 * k2;
            if (i < 384) ((float4*)scav)[i] = c4p[i];
        }
        __builtin_amdgcn_sched_barrier(0);
#pragma unroll
        for (int j = 0; j < 8; ++j) {
#pragma unroll
            for (int e = 0; e < 4; ++e) {
                int cell = qv[j] * 4 + e;
                int sw = chv[j] ^ (((e ^ qv[j]) & 1) << 4);
                tile[cell * HID + sw] = ((const u32*)&ld[j])[e];
            }
        }
        __syncthreads();

        int cell = t >> 4, kk = t & 15;
        int cg = c0 + cell;
        int lasc = (lasb[cg >> 5] >> (cg & 31)) & 1;
        int swb = ((cell ^ (cell >> 2)) & 1) << 4;
        const u32* trow = &tile[cell * HID];
        float sa = 0.f, sa2 = 0.f, mx = 0.f;
#pragma unroll 8
        for (int i = 0; i < 32; ++i) {
            int ch = kk + 16 * i;
            float2 vf = unph2(trow[ch ^ swb]);
            float vx = vf.x, vy = vf.y;
            if (lasc) {
                float r = sqrtf(fmaf(vx, vx, vy * vy));
                float lk = 0.3f * scav[1024 + ch] + 0.7f * atan2f(vy, vx);
                float sn, cs;
                __sincosf(lk, &sn, &cs);
                vx = r * cs; vy = r * sn;
            }
            vx += 0.05f * scav[ch];
            vy += 0.05f * scav[512 + ch];
            float a2v = fmaf(vx, vx, vy * vy);
            float a = sqrtf(a2v);
            sa += a; sa2 += a2v; mx = fmaxf(mx, a);
        }
        // per-cell reduce over the 16 lanes of the cell group
#pragma unroll
        for (int o = 1; o < 16; o <<= 1) {
            sa += __shfl_xor(sa, o, 64);
            sa2 += __shfl_xor(sa2, o, 64);
            mx = fmaxf(mx, __shfl_xor(mx, o, 64));
        }
        float invm = 1.f / (mx + 1e-8f);
        float s1 = sa * invm, s2 = sa2 * invm * invm;
        // sum the 4 cell groups of the wave
        s1 += __shfl_xor(s1, 16, 64); s2 += __shfl_xor(s2, 16, 64);
        s1 += __shfl_xor(s1, 32, 64); s2 += __shfl_xor(s2, 32, 64);
        if (lane == 0) { w1[wid] = s1; w2[wid] = s2; }
        __syncthreads();
        if (t == 0) {
            vpart[b] = make_float2(w1[0] + w1[1] + w1[2] + w1[3],
                                   w2[0] + w2[1] + w2[2] + w2[3]);
            __threadfence();
            int old = atomicAdd(cnt2, 1);
            slast = (old == CELL_BLOCKS - 1) ? 1 : 0;
        }
        __syncthreads();
        if (slast) {
            __threadfence();
            double d1 = (double)vpart[t].x + (double)vpart[t + 256].x
                      + (double)vpart[t + 512].x + (double)vpart[t + 768].x;
            double d2 = (double)vpart[t].y + (double)vpart[t + 256].y
                      + (double)vpart[t + 512].y + (double)vpart[t + 768].y;
#pragma unroll
            for (int o = 32; o; o >>= 1) { d1 += __shfl_xor(d1, o, 64); d2 += __shfl_xor(d2, o, 64); }
            if (lane == 0) { l1s[wid] = d1; l2s[wid] = d2; }
            __syncthreads();
            if (t == 0) {
                double t1 = l1s[0] + l1s[1] + l1s[2] + l1s[3];
                double t2 = l2s[0] + l2s[1] + l2s[2] + l2s[3];
                double nn = (double)N_CELLS * (double)HID;
                double mean = t1 / nn;
                out[IND] = (float)(t2 / nn - mean * mean);
            }
        }
    } else {
        // ---- pred role: wave wid computes row j; cavity read direct (L2-hot) ----
        int j = (b - CELL_BLOCKS) * 4 + wid;
        const float4* w4 = (const float4*)(dW + (size_t)j * (2 * HID));
        const float4* o4 = (const float4*)cavws;
        float a2 = 0.f;
#pragma unroll
        for (int tt = 0; tt < 4; ++tt) {
            float4 a = w4[lane + 64 * tt];
            float4 bx = o4[lane + 64 * tt];
            a2 += a.x * bx.x + a.y * bx.y + a.z * bx.z + a.w * bx.w;
        }
#pragma unroll
        for (int o = 32; o; o >>= 1) a2 += __shfl_xor(a2, o, 64);
        if (lane == 0) out[j] = a2 + db[j];
    }
}

// ---------------------------------------------------------------------------
extern "C" void kernel_launch(void* const* d_in, const int* in_sizes, int n_in,
                              void* d_out, int out_size, void* d_ws, size_t ws_size,
                              hipStream_t stream) {
    const float* x       = (const float*)d_in[0];
    const float* pump_W  = (const float*)d_in[1];
    const float* pump_b  = (const float*)d_in[2];
    const float* dec_W   = (const float*)d_in[3];
    const float* dec_b   = (const float*)d_in[4];
    const float* cs_re   = (const float*)d_in[5];
    const float* cs_im   = (const float*)d_in[6];
    const float* excited = (const float*)d_in[7];
    const float* pvel    = (const float*)d_in[8];
    const float* cav_re  = (const float*)d_in[9];
    const float* cav_im  = (const float*)d_in[10];
    // d_in[11] (neighbors) not needed: hypercube+ring recomputed on-chip

    float* out = (float*)d_out;
    char* ws = (char*)d_ws;
    int*    cnt   = (int*)(ws + CNT_OFF);
    u32*    lasb  = (u32*)(ws + LASB_OFF);
    float2* emisT = (float2*)(ws + EMIS_OFF);
    float*  cavws = (float*)(ws + CAV_OFF);
    float2* vpart = (float2*)(ws + VPART_OFF);
    u32*    yt    = (u32*)(ws + ROT_OFF);
    u32*    nstT  = (u32*)(ws + NST_OFF);

    hipMemsetAsync(ws, 0, 4096, stream);     // counters + lasing bitmask
    k_front<<<ROT_BLOCKS + PUMP_BLOCKS, 256, 0, stream>>>(
        cs_re, cs_im, pvel, yt, x, pump_W, pump_b, excited, lasb);
    k_coup<<<HID, 1024, 0, stream>>>(yt, lasb, nstT, emisT, cav_re, cav_im, cavws, cnt);
    k_finall<<<CELL_BLOCKS + PRED_BLOCKS, 256, 0, stream>>>(
        nstT, lasb, cavws, dec_W, dec_b, vpart, cnt + 1, out);
}

// Round 7
// 262.904 us; speedup vs baseline: 1.0061x; 1.0061x over previous
//
#include <hip/hip_runtime.h>
#include <hip/hip_fp16.h>
#include <math.h>

#define N_CELLS 16384
#define HID 512
#define IND 512

// ---- k_front roles ----
#define ROT_BLOCKS  4096    // 256 cell-tiles x 16 ch-tiles, each 64 cells x 32 ch
#define PUMP_BLOCKS 1024    // 16 cells per block

// ---- k_finall ----
#define CPB 16                          // cells per cell-block
#define CELL_BLOCKS (N_CELLS / CPB)     // 1024
#define PRED_BLOCKS 128                 // 4 pred rows per block

// ---- workspace layout (bytes) ----
#define CNT_OFF   0                                   // int[2]: gates (memset to 0)
#define LASB_OFF  1024                                // u32[512]: lasing bitmask (memset to 0)
#define EMIS_OFF  8192                                // float2[512]: per-channel emission sums
#define CAV_OFF   16384                               // float[1536]: cav_new re|im|old phase
#define VPART_OFF 32768                               // float2[CELL_BLOCKS]
#define ROT_OFF   (1<<20)                             // u32 Y^T[512][16384]: packed half2(re,im)
#define NST_OFF   (ROT_OFF + (size_t)N_CELLS*HID*4)   // u32 NST^T[512][16384]

typedef unsigned int u32;

__device__ inline __half2 u2h(u32 u) { union { u32 u; __half2 h; } x; x.u = u; return x.h; }
__device__ inline u32 h2u(__half2 h) { union { u32 u; __half2 h; } x; x.h = h; return x.u; }
__device__ inline u32 packh2(float re, float im) { return h2u(__floats2half2_rn(re, im)); }
__device__ inline float2 unph2(u32 u) { __half2 h = u2h(u); return make_float2(__low2float(h), __high2float(h)); }

#if __has_builtin(__builtin_amdgcn_fdot2)
typedef _Float16 hv2 __attribute__((ext_vector_type(2)));
__device__ inline float dot2u(u32 a, u32 b) {
    union { u32 u; hv2 h; } x, y; x.u = a; y.u = b;
    return __builtin_amdgcn_fdot2(x.h, y.h, 0.f, false);   // re*re' + im*im' in f32
}
#else
__device__ inline float dot2u(u32 a, u32 b) {
    float2 af = unph2(a), bf = unph2(b);
    return fmaf(af.x, bf.x, af.y * bf.y);
}
#endif

// Async 16B global->LDS. l is the PER-LANE dest; HW semantics are
// wave-uniform-base + lane*16, so subtract lane*16 (uniform result).
__device__ inline void cp16(const void* g, void* l) {
#if __has_builtin(__builtin_amdgcn_global_load_lds)
    char* base = (char*)l - (size_t)((threadIdx.x & 63) * 16);
    __builtin_amdgcn_global_load_lds(
        (const __attribute__((address_space(1))) unsigned int*)g,
        (__attribute__((address_space(3))) unsigned int*)base, 16, 0, 0);
#else
    *(uint4*)l = *(const uint4*)g;
#endif
}

// acc += d * q  where d = y.q  (cos-coupling identity on y = s/sqrt(|s|))
__device__ inline void accnb(__half2& acc, u32 y, u32 q) {
    float d = dot2u(y, q);
    acc = __hfma2(__float2half2_rn(d), u2h(q), acc);
}

// new = 0.7*s + 0.002*|s|^{-1/2}*acc ; s = |s|^{1/2} * y ; emission sum if lasing
__device__ inline u32 fincell(u32 y, __half2 acc, int las, float& emR, float& emI) {
    float2 yf = unph2(y);
    float a  = fmaf(yf.x, yf.x, yf.y * yf.y);   // |y|^2 = |s|
    float rs = rsqrtf(a);
    float sq = a * rs;
    float2 af = make_float2(__low2float(acc), __high2float(acc));
    float nr = 0.7f * sq * yf.x + 0.002f * rs * af.x;
    float ni = 0.7f * sq * yf.y + 0.002f * rs * af.y;
    if (las) { emR += nr; emI += ni; }
    return packh2(nr, ni);
}

// rotate by exp(i*0.1*w), scale by |s|^{-1/2}, pack half2(re,im)
__device__ inline u32 rot1(float re, float im, float w) {
    float sc = rsqrtf(sqrtf(fmaf(re, re, im * im)));
    float s, c;
    __sincosf(0.1f * w, &s, &c);
    return packh2((re * c - im * s) * sc, (re * s + im * c) * sc);
}

__device__ inline float dot4(float4 a, float4 b) {
    return a.x * b.x + a.y * b.y + a.z * b.z + a.w * b.w;
}

// ---------------------------------------------------------------------------
// Kernel 1 rot role: async-DMA stage raw cr/ci/pv f32 tile (64c x 32ch, 24KB)
// into LDS -> rot1 from LDS -> pitch-65 transpose tile -> coalesced yt store.
// Zero VGPR staging (round-6 lesson: compiler re-serializes reg-staged loads;
// VGPR stuck at 36). Pump role: 16 cells/block, bitmask lasing output.
__global__ __launch_bounds__(256, 4) void k_front(const float* __restrict__ cr,
        const float* __restrict__ ci, const float* __restrict__ pv,
        u32* __restrict__ yt,
        const float* __restrict__ x, const float* __restrict__ pW,
        const float* __restrict__ pb, const float* __restrict__ excited,
        u32* __restrict__ lasb) {
    int b = blockIdx.x, tid = threadIdx.x;
    if (b < ROT_BLOCKS) {
        __shared__ __align__(16) float sA[2048], sB[2048], sW[2048];  // 8KB each
        __shared__ __align__(16) u32 tile[32 * 65];                   // 8.3KB
        int cb = b >> 4, hb = b & 15;
        size_t goff = (size_t)cb * 64 * 2048 + (size_t)hb * 128;      // bytes
        const char* gA = (const char*)cr + goff;
        const char* gB = (const char*)ci + goff;
        const char* gW = (const char*)pv + goff;
#pragma unroll
        for (int k = 0; k < 2; ++k) {
            int o = tid * 16 + k * 4096;
            size_t go = (size_t)(o >> 7) * 2048 + (o & 127);
            cp16(gA + go, (char*)sA + o);
            cp16(gB + go, (char*)sB + o);
            cp16(gW + go, (char*)sW + o);
        }
        __syncthreads();                              // vmcnt(0) drain
        int cell = tid >> 2, q = tid & 3;
        const float4* a4 = (const float4*)sA + cell * 8 + q * 2;
        const float4* b4 = (const float4*)sB + cell * 8 + q * 2;
        const float4* w4 = (const float4*)sW + cell * 8 + q * 2;
        float4 A0 = a4[0], A1 = a4[1];
        float4 B0 = b4[0], B1 = b4[1];
        float4 W0 = w4[0], W1 = w4[1];
        int ch8 = q * 8;
        u32* tp = &tile[cell];
        tp[(ch8 + 0) * 65] = rot1(A0.x, B0.x, W0.x);
        tp[(ch8 + 1) * 65] = rot1(A0.y, B0.y, W0.y);
        tp[(ch8 + 2) * 65] = rot1(A0.z, B0.z, W0.z);
        tp[(ch8 + 3) * 65] = rot1(A0.w, B0.w, W0.w);
        tp[(ch8 + 4) * 65] = rot1(A1.x, B1.x, W1.x);
        tp[(ch8 + 5) * 65] = rot1(A1.y, B1.y, W1.y);
        tp[(ch8 + 6) * 65] = rot1(A1.z, B1.z, W1.z);
        tp[(ch8 + 7) * 65] = rot1(A1.w, B1.w, W1.w);
        __syncthreads();
#pragma unroll
        for (int g2 = 0; g2 < 2; ++g2) {
            int idx = tid + 256 * g2;                 // 0..511
            int chr = idx >> 4, c4 = idx & 15;
            uint4 v;
            v.x = tile[chr * 65 + c4 * 4 + 0];
            v.y = tile[chr * 65 + c4 * 4 + 1];
            v.z = tile[chr * 65 + c4 * 4 + 2];
            v.w = tile[chr * 65 + c4 * 4 + 3];
            ((uint4*)(yt + (size_t)(hb * 32 + chr) * N_CELLS + cb * 64))[c4] = v;
        }
    } else {
        // ---- pump: block = 16 cells; 16 lanes per cell read the 512-row ----
        int c0 = (b - ROT_BLOCKS) * 16;
        int cell = c0 + (tid >> 4);
        int l16 = tid & 15;
        int lane = tid & 63;
        const float4* w4 = (const float4*)(pW + (size_t)cell * IND);
        const float4* x4 = (const float4*)x;
        float4 wv[8];
#pragma unroll
        for (int k = 0; k < 8; ++k) wv[k] = w4[l16 + 16 * k];
        float acc = 0.f;
#pragma unroll
        for (int k = 0; k < 8; ++k) acc += dot4(wv[k], x4[l16 + 16 * k]);
#pragma unroll
        for (int o = 1; o < 16; o <<= 1) acc += __shfl_xor(acc, o, 64);
        int flag = 0;
        if (l16 == 0) {
            float p = 1.f / (1.f + expf(-(acc + pb[cell])));
            float e = excited[cell] * 0.95f + p * 0.05f;
            e = fminf(fmaxf(e, 0.f), 1.f);
            flag = (e > 0.5f) ? 1 : 0;
        }
        unsigned long long bal = __ballot(flag);      // bits 0,16,32,48 valid
        if (lane == 0) {
            u32 val = (u32)(bal & 1) | ((u32)(bal >> 16) & 1) << 1
                    | ((u32)(bal >> 32) & 1) << 2 | ((u32)(bal >> 48) & 1) << 3;
            atomicOr(&lasb[cell >> 5], val << (cell & 31));
        }
    }
}

// ---------------------------------------------------------------------------
// Kernel 2: neighbor coupling, one block per CHANNEL, 1024 threads. Column
// staged by 4 async DMA calls (zero VGPR). Lasing from 2KB bitmask.
// Counter-gated tail computes cavity_new + old phase once.
__global__ __launch_bounds__(1024, 8) void k_coup(const u32* __restrict__ yt,
                                                  const u32* __restrict__ lasb,
                                                  u32* __restrict__ nstT,
                                                  float2* __restrict__ emisT,
                                                  const float* __restrict__ cavr,
                                                  const float* __restrict__ cavi,
                                                  float* __restrict__ cavws,
                                                  int* __restrict__ cnt) {
    __shared__ __align__(16) u32 col[N_CELLS];          // exactly 64 KiB
    int ch = blockIdx.x, tid = threadIdx.x;
    const char* gsrc = (const char*)(yt + (size_t)ch * N_CELLS);
#pragma unroll
    for (int k = 0; k < 4; ++k)
        cp16(gsrc + tid * 16 + k * 16384, (char*)col + tid * 16 + k * 16384);
    __syncthreads();                                    // vmcnt(0) drain

    float emR = 0.f, emI = 0.f;
    int nlo = 0;
    uint4* outp = (uint4*)(nstT + (size_t)ch * N_CELLS);
#pragma unroll 2
    for (int j = 0; j < 4; ++j) {
        int s = tid + 1024 * j;
        u32 f = (lasb[s >> 3] >> ((s & 7) * 4)) & 0xF;  // 4 cells' flags
        int c = s << 2;                                 // quad base cell
        uint4 sq = *(const uint4*)&col[c];
        __half2 z = __floats2half2_rn(0.f, 0.f);
        __half2 a0 = z, a1 = z, a2 = z, a3 = z;
#pragma unroll
        for (int bb = 2; bb < 14; ++bb) {               // 12 external flips
            uint4 q = *(const uint4*)&col[c ^ (1 << bb)];
            accnb(a0, sq.x, q.x);
            accnb(a1, sq.y, q.y);
            accnb(a2, sq.z, q.z);
            accnb(a3, sq.w, q.w);
        }
        u32 qm = col[(c - 1) & (N_CELLS - 1)];          // ring extra of cell c
        u32 qp = col[(c + 4) & (N_CELLS - 1)];          // ring extra of cell c+3
        accnb(a0, sq.x, sq.y); accnb(a0, sq.x, sq.z); accnb(a0, sq.x, qm);
        accnb(a1, sq.y, sq.x); accnb(a1, sq.y, sq.w); accnb(a1, sq.y, sq.z);
        accnb(a2, sq.z, sq.w); accnb(a2, sq.z, sq.x); accnb(a2, sq.z, sq.y);
        accnb(a3, sq.w, sq.z); accnb(a3, sq.w, sq.y); accnb(a3, sq.w, qp);
        nlo += __popc(f);
        uint4 ov;
        ov.x = fincell(sq.x, a0, f & 1, emR, emI);
        ov.y = fincell(sq.y, a1, f & 2, emR, emI);
        ov.z = fincell(sq.z, a2, f & 4, emR, emI);
        ov.w = fincell(sq.w, a3, f & 8, emR, emI);
        outp[s] = ov;
    }
    __syncthreads();                                    // col reads done -> scratch
#pragma unroll
    for (int o = 32; o; o >>= 1) {
        emR += __shfl_xor(emR, o, 64);
        emI += __shfl_xor(emI, o, 64);
        nlo += __shfl_xor(nlo, o, 64);
    }
    float* scr = (float*)col;
    int* iscr = (int*)col;
    int wid = tid >> 6, lane = tid & 63;
    if (lane == 0) { scr[wid] = emR; scr[16 + wid] = emI; iscr[32 + wid] = nlo; }
    __syncthreads();
    if (tid == 0) {
        float sr = 0.f, si = 0.f; int sn = 0;
#pragma unroll
        for (int k = 0; k < 16; ++k) { sr += scr[k]; si += scr[16 + k]; sn += iscr[32 + k]; }
        emisT[ch] = make_float2(sr, si);
        iscr[48] = sn;
        __threadfence();
        int old = atomicAdd(cnt, 1);
        iscr[49] = (old == HID - 1) ? 1 : 0;
    }
    __syncthreads();
    if (iscr[49]) {
        // ---- TAIL: compute cavity_new + old phase once ----
        __threadfence();
        int nl = iscr[48];
        float inv = (nl > 0) ? 0.2f / (float)nl : 0.f;
        if (tid < 512) {
            int i = tid;
            float crv = cavr[i], civ = cavi[i];
            float2 e = emisT[i];
            cavws[i]        = (nl > 0) ? 0.8f * crv + e.x * inv : crv;
            cavws[512 + i]  = (nl > 0) ? 0.8f * civ + e.y * inv : civ;
            cavws[1024 + i] = atan2f(civ, crv);
        }
    }
}

// ---------------------------------------------------------------------------
// Kernel 3: finalize + var + pred. Slab DMA'd LINEARLY into tile2[ch][cell]
// (8 async calls, zero VGPR). Reader mapping cell=t&15, chs=t>>4 gives <=2-way
// LDS banks (free). Per-cell reduce: shfl over chs within wave + 4-wave LDS
// combine.
__global__ __launch_bounds__(256, 4) void k_finall(const u32* __restrict__ nstT,
        const u32* __restrict__ lasb, const float* __restrict__ cavws,
        const float* __restrict__ dW, const float* __restrict__ db,
        float2* __restrict__ vpart, int* __restrict__ cnt2,
        float* __restrict__ out) {
    int b = blockIdx.x, t = threadIdx.x;
    int w = t >> 6, lane = t & 63;
    if (b < CELL_BLOCKS) {
        __shared__ __align__(16) u32 tile2[HID * CPB];  // [ch][cell] 32KB
        __shared__ __align__(16) float scav[1536];      // cav re|im|phase
        __shared__ float wm[4][16], ws1[4][16], ws2[4][16];
        __shared__ int slast;
        __shared__ double l1s[4], l2s[4];

        int c0 = b * CPB;
        const char* gbase = (const char*)nstT + (size_t)c0 * 4;
#pragma unroll
        for (int k = 0; k < 8; ++k) {
            int o = t * 16 + k * 4096;                  // byte in 32KB slab
            cp16(gbase + (size_t)(o >> 6) * (N_CELLS * 4) + (o & 63),
                 (char*)tile2 + o);
        }
        const float4* c4p = (const float4*)cavws;
#pragma unroll
        for (int k2 = 0; k2 < 2; ++k2) {
            int i = t + 256 * k2;
            if (i < 384) ((float4*)scav)[i] = c4p[i];
        }
        __syncthreads();                                // vmcnt(0) drain

        int cell = t & 15, chs = t >> 4;
        int cg = c0 + cell;
        int lasc = (lasb[cg >> 5] >> (cg & 31)) & 1;
        float sa = 0.f, sa2 = 0.f, mx = 0.f;
#pragma unroll 8
        for (int i = 0; i < 32; ++i) {
            int ch = chs + 16 * i;
            float2 vf = unph2(tile2[ch * 16 + cell]);
            float vx = vf.x, vy = vf.y;
            if (lasc) {
                float r = sqrtf(fmaf(vx, vx, vy * vy));
                float lk = 0.3f * scav[1024 + ch] + 0.7f * atan2f(vy, vx);
                float sn, cs;
                __sincosf(lk, &sn, &cs);
                vx = r * cs; vy = r * sn;
            }
            vx += 0.05f * scav[ch];
            vy += 0.05f * scav[512 + ch];
            float a2v = fmaf(vx, vx, vy * vy);
            float a = sqrtf(a2v);
            sa += a; sa2 += a2v; mx = fmaxf(mx, a);
        }
        // reduce over chs within wave (cell preserved: partners differ in chs)
        sa += __shfl_xor(sa, 16, 64); sa2 += __shfl_xor(sa2, 16, 64);
        mx = fmaxf(mx, __shfl_xor(mx, 16, 64));
        sa += __shfl_xor(sa, 32, 64); sa2 += __shfl_xor(sa2, 32, 64);
        mx = fmaxf(mx, __shfl_xor(mx, 32, 64));
        if (lane < 16) { wm[w][lane] = mx; ws1[w][lane] = sa; ws2[w][lane] = sa2; }
        __syncthreads();
        if (t < 16) {
            float m = fmaxf(fmaxf(wm[0][t], wm[1][t]), fmaxf(wm[2][t], wm[3][t]));
            float sA_ = ws1[0][t] + ws1[1][t] + ws1[2][t] + ws1[3][t];
            float sB_ = ws2[0][t] + ws2[1][t] + ws2[2][t] + ws2[3][t];
            float invm = 1.f / (m + 1e-8f);
            float s1 = sA_ * invm, s2 = sB_ * invm * invm;
#pragma unroll
            for (int o = 1; o < 16; o <<= 1) {
                s1 += __shfl_xor(s1, o, 64);
                s2 += __shfl_xor(s2, o, 64);
            }
            if (t == 0) vpart[b] = make_float2(s1, s2);
        }
        __syncthreads();
        if (t == 0) {
            __threadfence();
            int old = atomicAdd(cnt2, 1);
            slast = (old == CELL_BLOCKS - 1) ? 1 : 0;
        }
        __syncthreads();
        if (slast) {
            __threadfence();
            double d1 = (double)vpart[t].x + (double)vpart[t + 256].x
                      + (double)vpart[t + 512].x + (double)vpart[t + 768].x;
            double d2 = (double)vpart[t].y + (double)vpart[t + 256].y
                      + (double)vpart[t + 512].y + (double)vpart[t + 768].y;
#pragma unroll
            for (int o = 32; o; o >>= 1) { d1 += __shfl_xor(d1, o, 64); d2 += __shfl_xor(d2, o, 64); }
            if (lane == 0) { l1s[w] = d1; l2s[w] = d2; }
            __syncthreads();
            if (t == 0) {
                double t1 = l1s[0] + l1s[1] + l1s[2] + l1s[3];
                double t2 = l2s[0] + l2s[1] + l2s[2] + l2s[3];
                double nn = (double)N_CELLS * (double)HID;
                double mean = t1 / nn;
                out[IND] = (float)(t2 / nn - mean * mean);
            }
        }
    } else {
        // ---- pred role: wave w computes row j; cavity read direct (L2-hot) ----
        int j = (b - CELL_BLOCKS) * 4 + w;
        const float4* w4 = (const float4*)(dW + (size_t)j * (2 * HID));
        const float4* o4 = (const float4*)cavws;
        float a2 = 0.f;
#pragma unroll
        for (int tt = 0; tt < 4; ++tt) {
            float4 a = w4[lane + 64 * tt];
            float4 bx = o4[lane + 64 * tt];
            a2 += a.x * bx.x + a.y * bx.y + a.z * bx.z + a.w * bx.w;
        }
#pragma unroll
        for (int o = 32; o; o >>= 1) a2 += __shfl_xor(a2, o, 64);
        if (lane == 0) out[j] = a2 + db[j];
    }
}

// ---------------------------------------------------------------------------
extern "C" void kernel_launch(void* const* d_in, const int* in_sizes, int n_in,
                              void* d_out, int out_size, void* d_ws, size_t ws_size,
                              hipStream_t stream) {
    const float* x       = (const float*)d_in[0];
    const float* pump_W  = (const float*)d_in[1];
    const float* pump_b  = (const float*)d_in[2];
    const float* dec_W   = (const float*)d_in[3];
    const float* dec_b   = (const float*)d_in[4];
    const float* cs_re   = (const float*)d_in[5];
    const float* cs_im   = (const float*)d_in[6];
    const float* excited = (const float*)d_in[7];
    const float* pvel    = (const float*)d_in[8];
    const float* cav_re  = (const float*)d_in[9];
    const float* cav_im  = (const float*)d_in[10];
    // d_in[11] (neighbors) not needed: hypercube+ring recomputed on-chip

    float* out = (float*)d_out;
    char* ws = (char*)d_ws;
    int*    cnt   = (int*)(ws + CNT_OFF);
    u32*    lasb  = (u32*)(ws + LASB_OFF);
    float2* emisT = (float2*)(ws + EMIS_OFF);
    float*  cavws = (float*)(ws + CAV_OFF);
    float2* vpart = (float2*)(ws + VPART_OFF);
    u32*    yt    = (u32*)(ws + ROT_OFF);
    u32*    nstT  = (u32*)(ws + NST_OFF);

    hipMemsetAsync(ws, 0, 4096, stream);     // counters + lasing bitmask
    k_front<<<ROT_BLOCKS + PUMP_BLOCKS, 256, 0, stream>>>(
        cs_re, cs_im, pvel, yt, x, pump_W, pump_b, excited, lasb);
    k_coup<<<HID, 1024, 0, stream>>>(yt, lasb, nstT, emisT, cav_re, cav_im, cavws, cnt);
    k_finall<<<CELL_BLOCKS + PRED_BLOCKS, 256, 0, stream>>>(
        nstT, lasb, cavws, dec_W, dec_b, vpart, cnt + 1, out);
}